// Round 1
// baseline (481.180 us; speedup 1.0000x reference)
//
#include <hip/hip_runtime.h>
#include <cmath>

#define THREADS 256
#define ROWS 16   // rows per block; 16*429 floats = 27456 B LDS buffer

struct Tables { float cont[12]; float cw[12]; float ew[12]; };

static Tables make_tables() {
    Tables tb;
    tb.cont[0] = 0.0f;
    for (int j = 1; j < 12; j++) {
        // numpy: x = linspace(0, b, 2000) (step b/1999), dx = b/2000
        double b = (double)j;
        double s = 0.0;
        for (int k = 0; k < 2000; k++) {
            double x = b * (double)k / 1999.0;
            s += pow(0.8, x);
        }
        double integ = s * (b / 2000.0);
        tb.cont[j] = (float)(1.0 / integ);
    }
    for (int s = 0; s < 12; s++) {
        double w = pow(0.8, (double)s);
        tb.cw[s] = (float)w;
        tb.ew[s] = (float)(w + 1.0);
    }
    return tb;
}

__global__ void zero_acc(double* g) {
    if (threadIdx.x < 5) g[threadIdx.x] = 0.0;
}

__global__ __launch_bounds__(THREADS) void loss_main(
    const float* __restrict__ geo,   // (B,12,33)
    const float* __restrict__ mgo,   // (B,13,33)
    const int*   __restrict__ pos,   // (B,13)
    const int*   __restrict__ mgt,   // (B,13)
    double*      __restrict__ gacc,  // 5 doubles
    int B, Tables tb)
{
    __shared__ float buf[ROWS * 429];     // reused: mask chunk then geo chunk
    __shared__ int   s_pos[ROWS * 13];
    __shared__ int   s_mgt[ROWS * 13];
    __shared__ float s_ce[ROWS * 12];
    __shared__ int   s_corr[ROWS * 12];
    __shared__ float acc[5];              // mask_sum, valid_cnt, prefix, correct, error

    const int t = threadIdx.x;
    const long long row0 = (long long)blockIdx.x * ROWS;
    const int nrows = min(ROWS, (int)(B - row0));
    if (nrows <= 0) return;   // block-uniform

    if (t < 5) acc[t] = 0.0f;
    for (int i = t; i < nrows * 13; i += THREADS) {
        s_pos[i] = pos[row0 * 13 + i];
        s_mgt[i] = mgt[row0 * 13 + i];
    }
    {   // stage mask chunk (coalesced float4; scalar tail if nrows%4 != 0)
        const float* src = mgo + row0 * 429;
        int nf = nrows * 429;
        int nf4 = nf >> 2;
        const float4* src4 = reinterpret_cast<const float4*>(src);
        float4* dst4 = reinterpret_cast<float4*>(buf);
        for (int i = t; i < nf4; i += THREADS) dst4[i] = src4[i];
        for (int i = (nf4 << 2) + t; i < nf; i += THREADS) buf[i] = src[i];
    }
    __syncthreads();

    // mask CE: one thread per (row, s), 16*13 = 208 tasks
    if (t < nrows * 13) {
        const int r = t / 13, s = t - r * 13;
        const float* x = buf + r * 429 + s * 33;   // stride 33: LDS conflict-free
        float m = x[0];
        #pragma unroll
        for (int k = 1; k < 33; k++) m = fmaxf(m, x[k]);
        float sum = 0.0f;
        #pragma unroll
        for (int k = 0; k < 33; k++) sum += expf(x[k] - m);
        float lse = logf(sum) + m;
        int tg = s_mgt[t];
        int tc = tg < 0 ? 0 : (tg > 32 ? 32 : tg);
        float ce = lse - x[tc];
        if (tg != -100) {
            atomicAdd(&acc[0], ce);
            atomicAdd(&acc[1], 1.0f);
        }
    }
    __syncthreads();   // buf reads done before overwrite

    {   // stage geo chunk (nrows*396 always divisible by 4)
        const float* src = geo + row0 * 396;
        int nf4 = (nrows * 396) >> 2;
        const float4* src4 = reinterpret_cast<const float4*>(src);
        float4* dst4 = reinterpret_cast<float4*>(buf);
        for (int i = t; i < nf4; i += THREADS) dst4[i] = src4[i];
    }
    __syncthreads();

    // geo CE + argmax: one thread per (row, s), 16*12 = 192 tasks
    if (t < nrows * 12) {
        const int r = t / 12, s = t - r * 12;
        const float* x = buf + r * 396 + s * 33;
        float m = x[0]; int am = 0;
        #pragma unroll
        for (int k = 1; k < 33; k++) { float v = x[k]; if (v > m) { m = v; am = k; } }
        float sum = 0.0f;
        #pragma unroll
        for (int k = 0; k < 33; k++) sum += expf(x[k] - m);
        float lse = logf(sum) + m;
        int tg = s_pos[r * 13 + s + 1];
        int tc = tg < 0 ? 0 : (tg > 32 ? 32 : tg);
        float ce = (tg == 32) ? 0.0f : (lse - x[tc]);  // ignore_index = V-1 = 32
        s_ce[t] = ce;
        s_corr[t] = (am == tg) ? 1 : 0;
    }
    __syncthreads();

    // per-row: first-error index (argmin semantics: first 0, else 0) + weighted sums
    if (t < nrows) {
        int mi = 0;
        for (int s = 0; s < 12; s++) { if (!s_corr[t * 12 + s]) { mi = s; break; } }
        float cont = tb.cont[mi];
        float ps = 0.0f, cs = 0.0f, es = 0.0f;
        for (int s = 0; s < 12; s++) {
            float ce = s_ce[t * 12 + s];
            if (s < mi) ps += ce * cont;
            if (s_corr[t * 12 + s]) cs += ce * tb.cw[s];
            else                    es += ce * tb.ew[s];
        }
        atomicAdd(&acc[2], ps);
        atomicAdd(&acc[3], cs);
        atomicAdd(&acc[4], es);
    }
    __syncthreads();
    if (t < 5) atomicAdd(&gacc[t], (double)acc[t]);
}

__global__ void finalize(const double* __restrict__ g,
                         const float* __restrict__ aux,
                         const float* __restrict__ taux,
                         const float* __restrict__ sigma,
                         float* __restrict__ out, double denom)
{
    double mask_loss = g[0] / fmax(g[1], 1.0);
    double prefix = g[2] / denom;
    double corr   = g[3] / denom;
    double err    = g[4] / denom;
    double geo = prefix + corr + err;
    double L[4] = { geo, mask_loss, (double)aux[0], (double)taux[0] };
    double w = 0.0, prod = 1.0;
    for (int i = 0; i < 4; i++) {
        double sg = (double)sigma[i];
        w += 0.5 * L[i] / (sg * sg);
        prod *= sg;
    }
    w += log(prod);
    out[0] = (float)w;
    out[1] = (float)prefix;
    out[2] = (float)corr;
    out[3] = (float)err;
    out[4] = (float)mask_loss;
}

extern "C" void kernel_launch(void* const* d_in, const int* in_sizes, int n_in,
                              void* d_out, int out_size, void* d_ws, size_t ws_size,
                              hipStream_t stream)
{
    static Tables tb = make_tables();   // host-only compute, graph-capture safe

    const float* geo   = (const float*)d_in[0];
    const float* mgo   = (const float*)d_in[1];
    const int*   pos   = (const int*)d_in[2];
    const int*   mgt   = (const int*)d_in[3];
    const float* aux   = (const float*)d_in[4];
    const float* taux  = (const float*)d_in[5];
    const float* sigma = (const float*)d_in[6];
    float* out = (float*)d_out;

    int B = in_sizes[2] / 13;
    double* gacc = (double*)d_ws;

    hipLaunchKernelGGL(zero_acc, dim3(1), dim3(64), 0, stream, gacc);
    int grid = (B + ROWS - 1) / ROWS;
    hipLaunchKernelGGL(loss_main, dim3(grid), dim3(THREADS), 0, stream,
                       geo, mgo, pos, mgt, gacc, B, tb);
    hipLaunchKernelGGL(finalize, dim3(1), dim3(1), 0, stream,
                       gacc, aux, taux, sigma, out, (double)B * 12.0);
}